// Round 13
// baseline (786.330 us; speedup 1.0000x reference)
//
#include <hip/hip_runtime.h>

// Mesh2: out3 = [out1||out2] @ W_comb^T + b_comb ; out4 = mean(self+3nbrs) @ W_agg^T + b_agg
// Architecture (R5+): Y = out2@Wa^T (bf16, ws); out4 = 0.25*(Y[n]+sum Y[nbr]) + b via
//   output-space gather (~125us, proven). gemm history: all reg-staged variants 390-550us,
//   ~2.2-2.8 TB/s, everything idle. R12 proved clean-traffic prefetch w/ 128 VGPR still loses:
//   register-staged loads serialize at the vmcnt-on-reg wait; occupancy halved.
// R13: global_load_lds DMA pipeline (the +67% ladder lever, never tried):
//   4 K-phases x 128 cols, f32 staged direct to LDS (16KB dbuf x2), DMA(p+1) issued after the
//   phase-top barrier -> async under compute(p). f32->bf16 conversion folded into frag reads.
//   Source-side XOR swizzle (chunk ^= row&7) + same XOR on reads: 16-way -> 2-way (free).
//   NO nontemporal stores (R10: nt = 4x writes). out3 scalar stores (clean per R9/R12).

typedef __bf16 bf16x8 __attribute__((ext_vector_type(8)));
typedef float f32x4 __attribute__((ext_vector_type(4)));

#define N_NODES 200000
#define BM 32
#define NTILES (N_NODES / BM)  // 6250
#define ROWC 520               // bf16 bounce row stride
#define ROWA 264               // fallback only
#define GRID_B 2048

__device__ __forceinline__ unsigned short f2bf(float x) {
  union { float f; unsigned int u; } v; v.f = x;
  return (unsigned short)((v.u + 0x7FFFu + ((v.u >> 16) & 1u)) >> 16);  // RNE
}

__device__ __forceinline__ void st_bf4(unsigned short* p, float4 f) {
  uint2 w;
  w.x = (unsigned int)f2bf(f.x) | ((unsigned int)f2bf(f.y) << 16);
  w.y = (unsigned int)f2bf(f.z) | ((unsigned int)f2bf(f.w) << 16);
  *reinterpret_cast<uint2*>(p) = w;
}

// async 16B global->LDS DMA. LDS dest = wave-uniform base + lane*16 (HW rule).
__device__ __forceinline__ void gload16(const void* g, void* l) {
  __builtin_amdgcn_global_load_lds((const __attribute__((address_space(1))) void*)g,
                                   (__attribute__((address_space(3))) void*)l, 16, 0, 0);
}

// Pack W (f32, row-major [O][K]) -> bf16 MFMA-B-fragment-linear layout:
// tile (nt,kt): lane l holds W[nt*16 + (l&15)][kt*32 + (l>>4)*8 + j] at P[tile*512 + l*8 + j].
__global__ void pack_w_kernel(const float* __restrict__ Wc,
                              const float* __restrict__ Wa,
                              unsigned short* __restrict__ Pc,
                              unsigned short* __restrict__ Pa) {
  int t = blockIdx.x * 256 + threadIdx.x;
  if (t >= (512 + 256) * 64) return;
  int lane = t & 63;
  int tile = t >> 6;
  const float* W;
  unsigned short* P;
  int K, kt_n;
  if (tile < 512) { W = Wc; P = Pc; K = 512; kt_n = 16; }
  else { tile -= 512; W = Wa; P = Pa; K = 256; kt_n = 8; }
  int nt = tile / kt_n;
  int kt = tile - nt * kt_n;
  int row = nt * 16 + (lane & 15);
  int k0 = kt * 32 + (lane >> 4) * 8;
  const float* src = W + (size_t)row * K + k0;
  unsigned short* dst = P + (size_t)tile * 512 + lane * 8;
#pragma unroll
  for (int j = 0; j < 8; ++j) dst[j] = f2bf(src[j]);
}

// ---------------- Kernel A: DMA-pipelined GEMM (out3 f32 + Y bf16) ----------------
__global__ __launch_bounds__(512, 2) void gemm_kernel(
    const float* __restrict__ out1, const float* __restrict__ out2,
    const unsigned short* __restrict__ Pc, const unsigned short* __restrict__ Pa,
    const float* __restrict__ b_comb,
    float* __restrict__ out3, unsigned short* __restrict__ Y) {
  // union: 2 x 16KB f32 phase buffers | 32x520 bf16 Y-bounce (33280 B)
  __shared__ __align__(16) unsigned char smem[33280];

  const int tid = threadIdx.x;
  const int wave = tid >> 6, lane = tid & 63;
  const int l15 = lane & 15, l4 = lane >> 4;
  const long long node0 = (long long)blockIdx.x * BM;
  const int nt0 = wave * 4;

  float bcv[4];
#pragma unroll
  for (int n = 0; n < 4; ++n) bcv[n] = b_comb[wave * 64 + n * 16 + l15];

  // issue one phase's DMA: 16KB = 2 x (8 waves x 1KB). Source chunk XOR-permuted so that
  // physical LDS chunk c holds logical chunk c^(row&7)  (linear dest + inv-swz source).
  auto issueDMA = [&](int p, int bufByte) {
    const float* src = (p < 2) ? out1 : out2;
    const int colBase = (p & 1) * 128;
    {
      const int row = wave * 2 + (lane >> 5);           // 0..15
      const int c = lane & 31;
      const float* g = src + (node0 + row) * 256 + colBase + ((c ^ (row & 7)) << 2);
      gload16(g, smem + bufByte + wave * 1024);
    }
    {
      const int row = 16 + wave * 2 + (lane >> 5);      // 16..31
      const int c = lane & 31;
      const float* g = src + (node0 + row) * 256 + colBase + ((c ^ (row & 7)) << 2);
      gload16(g, smem + bufByte + 8192 + wave * 1024);
    }
  };

  // read A-fragment (row, kt) from phase buffer: 2 x 16B f32 chunks (swizzled) -> bf16x8
  auto readA = [&](int bufByte, int row, int kt) -> bf16x8 {
    const int c0 = kt * 8 + l4 * 2;
    const int r7 = row & 7;
    const float4 f0 =
        *reinterpret_cast<const float4*>(smem + bufByte + row * 512 + ((c0 ^ r7) << 4));
    const float4 f1 =
        *reinterpret_cast<const float4*>(smem + bufByte + row * 512 + (((c0 + 1) ^ r7) << 4));
    bf16x8 a;
    a[0] = (__bf16)f0.x; a[1] = (__bf16)f0.y; a[2] = (__bf16)f0.z; a[3] = (__bf16)f0.w;
    a[4] = (__bf16)f1.x; a[5] = (__bf16)f1.y; a[6] = (__bf16)f1.z; a[7] = (__bf16)f1.w;
    return a;
  };

  f32x4 acc3[2][4], accY[2][4];
#pragma unroll
  for (int m = 0; m < 2; ++m)
#pragma unroll
    for (int n = 0; n < 4; ++n) {
      acc3[m][n] = (f32x4){0.f, 0.f, 0.f, 0.f};
      accY[m][n] = (f32x4){0.f, 0.f, 0.f, 0.f};
    }

  issueDMA(0, 0);
#pragma unroll
  for (int p = 0; p < 4; ++p) {
    const int b = (p & 1) * 16384;
    asm volatile("s_waitcnt vmcnt(0)" ::: "memory");  // my DMA slices for phase p landed
    __builtin_amdgcn_s_barrier();                     // all waves' slices landed
    __builtin_amdgcn_sched_barrier(0);                // no LDS reads hoisted above barrier
    if (p < 3) issueDMA(p + 1, ((p + 1) & 1) * 16384);  // async under compute(p)

#pragma unroll
    for (int kt = 0; kt < 4; ++kt) {
      bf16x8 a0 = readA(b, l15, kt);
      bf16x8 a1 = readA(b, l15 + 16, kt);
#pragma unroll
      for (int n = 0; n < 4; ++n) {
        bf16x8 bf = *reinterpret_cast<const bf16x8*>(
            Pc + ((size_t)(nt0 + n) * 16 + p * 4 + kt) * 512 + lane * 8);
        acc3[0][n] = __builtin_amdgcn_mfma_f32_16x16x32_bf16(a0, bf, acc3[0][n], 0, 0, 0);
        acc3[1][n] = __builtin_amdgcn_mfma_f32_16x16x32_bf16(a1, bf, acc3[1][n], 0, 0, 0);
      }
      if (p >= 2) {  // Y = out2 @ Wa^T reuses the same A-fragments
#pragma unroll
        for (int n = 0; n < 4; ++n) {
          bf16x8 bf = *reinterpret_cast<const bf16x8*>(
              Pa + ((size_t)(nt0 + n) * 8 + (p - 2) * 4 + kt) * 512 + lane * 8);
          accY[0][n] = __builtin_amdgcn_mfma_f32_16x16x32_bf16(a0, bf, accY[0][n], 0, 0, 0);
          accY[1][n] = __builtin_amdgcn_mfma_f32_16x16x32_bf16(a1, bf, accY[1][n], 0, 0, 0);
        }
      }
    }
  }

  // ---- out3 epilogue: scalar MFMA-layout stores (L2-merged clean, R9/R12 counters) ----
  {
    float* o3 = out3 + node0 * 512 + wave * 64 + l15;
#pragma unroll
    for (int m = 0; m < 2; ++m)
#pragma unroll
      for (int r = 0; r < 4; ++r) {
        float* pp = o3 + (long long)(m * 16 + l4 * 4 + r) * 512;
#pragma unroll
        for (int n = 0; n < 4; ++n) pp[n * 16] = acc3[m][n][r] + bcv[n];
      }
  }

  // ---- Y epilogue: LDS bounce -> coalesced uint4 stores (R7-proven) ----
  unsigned short* yl = reinterpret_cast<unsigned short*>(smem);
  __syncthreads();  // all phase-3 LDS reads complete before overwrite
#pragma unroll
  for (int m = 0; m < 2; ++m)
#pragma unroll
    for (int r = 0; r < 4; ++r) {
      const int row = m * 16 + l4 * 4 + r;
#pragma unroll
      for (int n = 0; n < 4; ++n)
        yl[row * ROWC + wave * 64 + n * 16 + l15] = f2bf(accY[m][n][r]);
    }
  __syncthreads();
  {
    const int row = tid >> 4, c16 = tid & 15;
    const unsigned short* src = yl + row * ROWC;
    unsigned short* dst = Y + (node0 + row) * 512;
#pragma unroll
    for (int j = 0; j < 4; ++j) {
      const int off = (c16 + 16 * j) * 8;
      *reinterpret_cast<uint4*>(dst + off) = *reinterpret_cast<const uint4*>(src + off);
    }
  }
}

// ---------------- Kernel B: out4 = 0.25*(Y[n]+Y[i0]+Y[i1]+Y[i2]) + b_agg ----------------
__device__ __forceinline__ float bf_lo(unsigned u) {
  union { unsigned x; float f; } c; c.x = u << 16; return c.f;
}
__device__ __forceinline__ float bf_hi(unsigned u) {
  union { unsigned x; float f; } c; c.x = u & 0xFFFF0000u; return c.f;
}

__global__ __launch_bounds__(256) void gather_kernel(
    const unsigned short* __restrict__ Y, const int* __restrict__ nbr,
    const float* __restrict__ b_agg, float* __restrict__ out4) {
  const int lane = threadIdx.x & 63;
  const int wid = (blockIdx.x * 256 + threadIdx.x) >> 6;
  const int nwaves = (GRID_B * 256) >> 6;

  float ba[8];
  const float* bp = b_agg + lane * 8;
#pragma unroll
  for (int j = 0; j < 8; ++j) ba[j] = bp[j];

  for (int n = wid; n < N_NODES; n += nwaves) {
    int i0 = nbr[3 * n + 0];
    int i1 = nbr[3 * n + 1];
    int i2 = nbr[3 * n + 2];
    i0 = i0 < 0 ? 0 : (i0 >= N_NODES ? N_NODES - 1 : i0);
    i1 = i1 < 0 ? 0 : (i1 >= N_NODES ? N_NODES - 1 : i1);
    i2 = i2 < 0 ? 0 : (i2 >= N_NODES ? N_NODES - 1 : i2);

    const uint4 a  = *reinterpret_cast<const uint4*>(Y + (size_t)n  * 512 + lane * 8);
    const uint4 b0 = *reinterpret_cast<const uint4*>(Y + (size_t)i0 * 512 + lane * 8);
    const uint4 b1 = *reinterpret_cast<const uint4*>(Y + (size_t)i1 * 512 + lane * 8);
    const uint4 b2 = *reinterpret_cast<const uint4*>(Y + (size_t)i2 * 512 + lane * 8);

    const unsigned wa[4] = {a.x, a.y, a.z, a.w};
    const unsigned w0[4] = {b0.x, b0.y, b0.z, b0.w};
    const unsigned w1[4] = {b1.x, b1.y, b1.z, b1.w};
    const unsigned w2[4] = {b2.x, b2.y, b2.z, b2.w};
    float s[8];
#pragma unroll
    for (int w = 0; w < 4; ++w) {
      s[2 * w]     = bf_lo(wa[w]) + bf_lo(w0[w]) + bf_lo(w1[w]) + bf_lo(w2[w]);
      s[2 * w + 1] = bf_hi(wa[w]) + bf_hi(w0[w]) + bf_hi(w1[w]) + bf_hi(w2[w]);
    }
    f32x4 o0 = {s[0] * 0.25f + ba[0], s[1] * 0.25f + ba[1],
                s[2] * 0.25f + ba[2], s[3] * 0.25f + ba[3]};
    f32x4 o1 = {s[4] * 0.25f + ba[4], s[5] * 0.25f + ba[5],
                s[6] * 0.25f + ba[6], s[7] * 0.25f + ba[7]};
    f32x4* op = reinterpret_cast<f32x4*>(out4 + (size_t)n * 512 + lane * 8);
    op[0] = o0;  // plain cached stores — nt inflates HBM writes 4x on gfx950 (R10)
    op[1] = o1;
  }
}

// ---------------- Fallback (R2-style, known-good) if ws too small for Y ----------------
__global__ __launch_bounds__(512, 4) void mesh_fused_fallback(
    const float* __restrict__ out1, const float* __restrict__ out2,
    const int* __restrict__ nbr,
    const unsigned short* __restrict__ Pc, const unsigned short* __restrict__ Pa,
    const float* __restrict__ b_comb, const float* __restrict__ b_agg,
    float* __restrict__ outp) {
  __shared__ unsigned short Ac[32 * ROWC];
  __shared__ unsigned short Aagg[32 * ROWA];
  const int tid = threadIdx.x;
  const long long node0 = (long long)blockIdx.x * 32;
  {
    const int ln = tid >> 4, c16 = tid & 15;
    const long long gn = node0 + ln;
    long long i0 = nbr[3 * gn + 0], i1 = nbr[3 * gn + 1], i2 = nbr[3 * gn + 2];
    i0 = i0 < 0 ? 0 : (i0 >= N_NODES ? N_NODES - 1 : i0);
    i1 = i1 < 0 ? 0 : (i1 >= N_NODES ? N_NODES - 1 : i1);
    i2 = i2 < 0 ? 0 : (i2 >= N_NODES ? N_NODES - 1 : i2);
    const float4* r1 = reinterpret_cast<const float4*>(out1 + gn * 256);
    const float4* r2 = reinterpret_cast<const float4*>(out2 + gn * 256);
    const float4* g0 = reinterpret_cast<const float4*>(out2 + i0 * 256);
    const float4* g1 = reinterpret_cast<const float4*>(out2 + i1 * 256);
    const float4* g2 = reinterpret_cast<const float4*>(out2 + i2 * 256);
#pragma unroll
    for (int r = 0; r < 4; ++r) {
      const int c = c16 + 16 * r;
      float4 f1 = r1[c], f2 = r2[c], n0 = g0[c], n1 = g1[c], n2 = g2[c];
      float4 ag;
      ag.x = (f2.x + n0.x + n1.x + n2.x) * 0.25f;
      ag.y = (f2.y + n0.y + n1.y + n2.y) * 0.25f;
      ag.z = (f2.z + n0.z + n1.z + n2.z) * 0.25f;
      ag.w = (f2.w + n0.w + n1.w + n2.w) * 0.25f;
      st_bf4(&Ac[ln * ROWC + c * 4], f1);
      st_bf4(&Ac[ln * ROWC + 256 + c * 4], f2);
      st_bf4(&Aagg[ln * ROWA + c * 4], ag);
    }
  }
  __syncthreads();
  const int wave = tid >> 6, lane = tid & 63;
  const int l15 = lane & 15, l4 = lane >> 4;
  const int nt0 = wave * 4;
  float* o3 = outp;
  float* o4 = outp + (size_t)N_NODES * 512;
  {
    f32x4 acc[2][4];
#pragma unroll
    for (int m = 0; m < 2; ++m)
#pragma unroll
      for (int n = 0; n < 4; ++n) acc[m][n] = (f32x4){0.f, 0.f, 0.f, 0.f};
    const unsigned short* pc = Pc + (size_t)nt0 * 16 * 512 + lane * 8;
    const unsigned short* ab = &Ac[(size_t)l15 * ROWC + l4 * 8];
#pragma unroll
    for (int kt = 0; kt < 16; ++kt) {
      bf16x8 a0 = *reinterpret_cast<const bf16x8*>(ab + kt * 32);
      bf16x8 a1 = *reinterpret_cast<const bf16x8*>(ab + 16 * ROWC + kt * 32);
#pragma unroll
      for (int n = 0; n < 4; ++n) {
        bf16x8 bb = *reinterpret_cast<const bf16x8*>(pc + ((size_t)n * 16 + kt) * 512);
        acc[0][n] = __builtin_amdgcn_mfma_f32_16x16x32_bf16(a0, bb, acc[0][n], 0, 0, 0);
        acc[1][n] = __builtin_amdgcn_mfma_f32_16x16x32_bf16(a1, bb, acc[1][n], 0, 0, 0);
      }
    }
#pragma unroll
    for (int m = 0; m < 2; ++m)
#pragma unroll
      for (int r = 0; r < 4; ++r)
#pragma unroll
        for (int n = 0; n < 4; ++n) {
          const int col = wave * 64 + n * 16 + l15;
          o3[(node0 + m * 16 + l4 * 4 + r) * 512 + col] = acc[m][n][r] + b_comb[col];
        }
  }
  {
    f32x4 acc[2][4];
#pragma unroll
    for (int m = 0; m < 2; ++m)
#pragma unroll
      for (int n = 0; n < 4; ++n) acc[m][n] = (f32x4){0.f, 0.f, 0.f, 0.f};
    const unsigned short* pa = Pa + (size_t)nt0 * 8 * 512 + lane * 8;
    const unsigned short* ab = &Aagg[(size_t)l15 * ROWA + l4 * 8];
#pragma unroll
    for (int kt = 0; kt < 8; ++kt) {
      bf16x8 a0 = *reinterpret_cast<const bf16x8*>(ab + kt * 32);
      bf16x8 a1 = *reinterpret_cast<const bf16x8*>(ab + 16 * ROWA + kt * 32);
#pragma unroll
      for (int n = 0; n < 4; ++n) {
        bf16x8 bb = *reinterpret_cast<const bf16x8*>(pa + ((size_t)n * 8 + kt) * 512);
        acc[0][n] = __builtin_amdgcn_mfma_f32_16x16x32_bf16(a0, bb, acc[0][n], 0, 0, 0);
        acc[1][n] = __builtin_amdgcn_mfma_f32_16x16x32_bf16(a1, bb, acc[1][n], 0, 0, 0);
      }
    }
#pragma unroll
    for (int m = 0; m < 2; ++m)
#pragma unroll
      for (int r = 0; r < 4; ++r)
#pragma unroll
        for (int n = 0; n < 4; ++n) {
          const int col = wave * 64 + n * 16 + l15;
          o4[(node0 + m * 16 + l4 * 4 + r) * 512 + col] = acc[m][n][r] + b_agg[col];
        }
  }
}

extern "C" void kernel_launch(void* const* d_in, const int* in_sizes, int n_in,
                              void* d_out, int out_size, void* d_ws, size_t ws_size,
                              hipStream_t stream) {
  const float* out1 = (const float*)d_in[0];
  const float* out2 = (const float*)d_in[1];
  const int* nbr = (const int*)d_in[2];  // harness pushes integers as int32
  const float* Wc = (const float*)d_in[3];
  const float* bc = (const float*)d_in[4];
  const float* Wa = (const float*)d_in[5];
  const float* ba = (const float*)d_in[6];

  const size_t yElems = (size_t)N_NODES * 512;     // bf16 Y: 204.8 MB
  const size_t packElems = 512 * 512 + 512 * 256;  // 768 KB
  const size_t need = (yElems + packElems) * 2;

  if (ws_size >= need) {
    unsigned short* Yw = (unsigned short*)d_ws;
    unsigned short* Pc = Yw + yElems;
    unsigned short* Pa = Pc + 512 * 512;
    pack_w_kernel<<<192, 256, 0, stream>>>(Wc, Wa, Pc, Pa);
    gemm_kernel<<<NTILES, 512, 0, stream>>>(out1, out2, Pc, Pa, bc, (float*)d_out, Yw);
    gather_kernel<<<GRID_B, 256, 0, stream>>>(Yw, nbr, ba,
                                              (float*)d_out + (size_t)N_NODES * 512);
  } else {
    unsigned short* Pc = (unsigned short*)d_ws;
    unsigned short* Pa = Pc + 512 * 512;
    pack_w_kernel<<<192, 256, 0, stream>>>(Wc, Wa, Pc, Pa);
    mesh_fused_fallback<<<N_NODES / 32, 512, 0, stream>>>(out1, out2, nbr, Pc, Pa, bc, ba,
                                                          (float*)d_out);
  }
}